// Round 1
// baseline (241.500 us; speedup 1.0000x reference)
//
#include <hip/hip_runtime.h>

typedef __attribute__((ext_vector_type(8))) short short8;
typedef __attribute__((ext_vector_type(4))) float f32x4;

#define LN_EPS 1e-5f
#define NSLOPE 0.01f

static __device__ __forceinline__ unsigned short f2bf(float f){
  union { float f; unsigned int u; } v; v.f = f;
  unsigned int u = v.u;
  unsigned int r = (u + 0x7FFFu + ((u >> 16) & 1u)) >> 16;
  return (unsigned short)r;
}
static __device__ __forceinline__ float bf2f(unsigned short h){
  union { unsigned int u; float f; } v; v.u = ((unsigned int)h) << 16;
  return v.f;
}

// ---------------- prep: convert weights to bf16 (and pad f1_w K 264->288) ----
__global__ void qnet_prep(const float* __restrict__ fc2_w, const float* __restrict__ fc3_w,
                          const float* __restrict__ f1_w,
                          unsigned short* __restrict__ fc2_bf, unsigned short* __restrict__ fc3_bf,
                          unsigned short* __restrict__ f1_bf){
  int i = blockIdx.x * 256 + threadIdx.x;
  if (i < 256*256) {
    fc2_bf[i] = f2bf(fc2_w[i]);
  } else if (i < 256*256 + 128*256) {
    int j = i - 256*256;
    fc3_bf[j] = f2bf(fc3_w[j]);
  } else {
    int j = i - (256*256 + 128*256);
    if (j < 512*288) {
      int o = j / 288, k = j % 288;
      f1_bf[j] = (k < 264) ? f2bf(f1_w[o*264 + k]) : (unsigned short)0;
    }
  }
}

// ---------------- LN + leaky-relu stage over 256 cols, bf16 in/out ----------
static __device__ __forceinline__ void ln_stage(
    const unsigned short (*src)[264], unsigned short (*dst)[264],
    const float* __restrict__ g, const float* __restrict__ bt, int wid, int lane)
{
  const int c0 = lane * 4;
  float4 gv = *(const float4*)(g + c0);
  float4 bv = *(const float4*)(bt + c0);
  for (int r = wid*16; r < wid*16 + 16; r++){
    ushort4 xr = *(const ushort4*)&src[r][c0];
    float x0 = bf2f(xr.x), x1 = bf2f(xr.y), x2 = bf2f(xr.z), x3 = bf2f(xr.w);
    float s  = x0 + x1 + x2 + x3;
    float s2 = x0*x0 + x1*x1 + x2*x2 + x3*x3;
    #pragma unroll
    for (int m = 1; m < 64; m <<= 1){ s += __shfl_xor(s, m, 64); s2 += __shfl_xor(s2, m, 64); }
    float mean = s * (1.f/256.f);
    float var  = s2 * (1.f/256.f) - mean*mean;
    float rstd = rsqrtf(var + LN_EPS);
    float y0 = (x0-mean)*rstd*gv.x + bv.x; y0 = (y0 >= 0.f) ? y0 : NSLOPE*y0;
    float y1 = (x1-mean)*rstd*gv.y + bv.y; y1 = (y1 >= 0.f) ? y1 : NSLOPE*y1;
    float y2 = (x2-mean)*rstd*gv.z + bv.z; y2 = (y2 >= 0.f) ? y2 : NSLOPE*y2;
    float y3 = (x3-mean)*rstd*gv.w + bv.w; y3 = (y3 >= 0.f) ? y3 : NSLOPE*y3;
    ushort4 o; o.x = f2bf(y0); o.y = f2bf(y1); o.z = f2bf(y2); o.w = f2bf(y3);
    *(ushort4*)&dst[r][c0] = o;
  }
}

// ---------------- main fused kernel: one block per b ------------------------
__global__ __launch_bounds__(256, 2) void qnet_main(
    const float* __restrict__ x_feats, const int* __restrict__ actions,
    const float* __restrict__ fc1_w, const float* __restrict__ fc1_b,
    const float* __restrict__ ln1_g, const float* __restrict__ ln1_b,
    const unsigned short* __restrict__ fc2_bf, const float* __restrict__ fc2_b,
    const float* __restrict__ ln2_g, const float* __restrict__ ln2_b,
    const unsigned short* __restrict__ fc3_bf, const float* __restrict__ fc3_b,
    unsigned short* __restrict__ fc_in)
{
  __shared__ float s_cur[4];
  __shared__ __align__(16) float s_nb[64][8];
  __shared__ float s_mask[64];
  __shared__ __align__(16) unsigned short s_act[64][264];
  __shared__ __align__(16) unsigned short s_pre[64][264];

  const int tid  = threadIdx.x;
  const int b    = blockIdx.x;
  const int wid  = tid >> 6, lane = tid & 63;
  const int lr   = lane & 15, lg = lane >> 4;

  // phase 1: load x row (3 + 64*5)
  const float* xr = x_feats + (size_t)b * 323;
  for (int i = tid; i < 323; i += 256){
    float v = xr[i];
    if (i < 3) s_cur[i] = v;
    else { int j = i - 3; s_nb[j / 5][j % 5] = v; }
  }
  if (tid < 64){ s_nb[tid][5] = 0.f; s_nb[tid][6] = 0.f; s_nb[tid][7] = 0.f; }
  __syncthreads();
  if (tid < 64){
    float m = (s_nb[tid][0] != 0.f || s_nb[tid][1] != 0.f || s_nb[tid][2] != 0.f ||
               s_nb[tid][3] != 0.f || s_nb[tid][4] != 0.f) ? 1.f : 0.f;
    s_mask[tid] = m;
  }

  // phase 2: layer1 (8 -> 256), thread = output dim d
  {
    const int d = tid;
    float w[8];
    #pragma unroll
    for (int f = 0; f < 8; f++) w[f] = fc1_w[d*8 + f];
    float base = fc1_b[d] + w[0]*s_cur[0] + w[1]*s_cur[1] + w[2]*s_cur[2];
    for (int n = 0; n < 64; n++){
      float4 nb4 = *(const float4*)&s_nb[n][0];
      float nb5  = s_nb[n][4];
      float acc = base + w[3]*nb4.x + w[4]*nb4.y + w[5]*nb4.z + w[6]*nb4.w + w[7]*nb5;
      s_pre[n][d] = f2bf(acc);
    }
  }
  __syncthreads();

  // phase 3: LN1 + lrelu -> s_act
  ln_stage(s_pre, s_act, ln1_g, ln1_b, wid, lane);
  __syncthreads();

  // phase 4: GEMM2: pre2[64][256] = h1 @ fc2_w^T; wave w owns cols 64w..64w+64
  {
    f32x4 acc[4][4];
    const f32x4 z = {0.f, 0.f, 0.f, 0.f};
    #pragma unroll
    for (int m = 0; m < 4; m++)
      #pragma unroll
      for (int t = 0; t < 4; t++) acc[m][t] = z;
    const unsigned short* bp[4];
    #pragma unroll
    for (int t = 0; t < 4; t++)
      bp[t] = fc2_bf + (size_t)(64*wid + 16*t + lr) * 256 + lg*8;
    #pragma unroll
    for (int kk = 0; kk < 8; kk++){
      const int k0 = kk*32 + lg*8;
      short8 a[4];
      #pragma unroll
      for (int m = 0; m < 4; m++) a[m] = *(const short8*)&s_act[16*m + lr][k0];
      #pragma unroll
      for (int t = 0; t < 4; t++){
        short8 bw = *(const short8*)(bp[t] + kk*32);
        #pragma unroll
        for (int m = 0; m < 4; m++)
          acc[m][t] = __builtin_amdgcn_mfma_f32_16x16x32_bf16(a[m], bw, acc[m][t], 0, 0, 0);
      }
    }
    #pragma unroll
    for (int t = 0; t < 4; t++){
      const int col = 64*wid + 16*t + lr;
      const float bias = fc2_b[col];
      #pragma unroll
      for (int m = 0; m < 4; m++)
        #pragma unroll
        for (int j = 0; j < 4; j++){
          const int row = 16*m + 4*lg + j;
          s_pre[row][col] = f2bf(acc[m][t][j] + bias);
        }
    }
  }
  __syncthreads();

  // phase 5: LN2 + lrelu -> s_act
  ln_stage(s_pre, s_act, ln2_g, ln2_b, wid, lane);
  __syncthreads();

  // phase 6: GEMM3: embeds[64][128] = h2 @ fc3_w^T + b; wave w owns cols 32w..32w+32
  {
    f32x4 acc[4][2];
    const f32x4 z = {0.f, 0.f, 0.f, 0.f};
    #pragma unroll
    for (int m = 0; m < 4; m++){ acc[m][0] = z; acc[m][1] = z; }
    #pragma unroll
    for (int kk = 0; kk < 8; kk++){
      const int k0 = kk*32 + lg*8;
      short8 a[4];
      #pragma unroll
      for (int m = 0; m < 4; m++) a[m] = *(const short8*)&s_act[16*m + lr][k0];
      #pragma unroll
      for (int t = 0; t < 2; t++){
        short8 bw = *(const short8*)(fc3_bf + (size_t)(32*wid + 16*t + lr) * 256 + k0);
        #pragma unroll
        for (int m = 0; m < 4; m++)
          acc[m][t] = __builtin_amdgcn_mfma_f32_16x16x32_bf16(a[m], bw, acc[m][t], 0, 0, 0);
      }
    }
    #pragma unroll
    for (int t = 0; t < 2; t++){
      const int col = 32*wid + 16*t + lr;
      const float bias = fc3_b[col];
      #pragma unroll
      for (int m = 0; m < 4; m++)
        #pragma unroll
        for (int j = 0; j < 4; j++){
          const int row = 16*m + 4*lg + j;
          s_pre[row][col] = f2bf(acc[m][t][j] + bias);  // embeds, bf16, cols 0..127
        }
    }
  }
  __syncthreads();

  // phase 7: mask-pool + gather -> fc_in[b][288]
  {
    const int aidx = actions[b];
    unsigned short* fo = fc_in + (size_t)b * 288;
    if (tid < 128){
      const int e = tid;
      float accp = 0.f, cnt = 0.f;
      for (int n = 0; n < 64; n++){
        float m = s_mask[n];
        cnt  += m;
        accp += m * bf2f(s_pre[n][e]);
      }
      cnt = fmaxf(cnt, 1.f);
      fo[131 + e] = f2bf(accp / cnt);   // pooled
      fo[3 + e]   = s_pre[aidx][e];     // chosen embed (already bf16)
    } else {
      const int t = tid - 128;
      if (t < 3)       fo[t] = f2bf(s_cur[t]);                 // cur_pos
      else if (t < 8)  fo[259 + (t-3)] = f2bf(s_nb[aidx][t-3]); // chosen states
      else if (t < 32) fo[264 + (t-8)] = 0;                     // zero pad K->288
    }
  }
}

// ---------------- head: fc_in[B][288] -> f1 -> LN -> lrelu -> f2 -> out[B] --
__global__ __launch_bounds__(256, 2) void qnet_head(
    const unsigned short* __restrict__ fc_in,   // [B][288] bf16
    const unsigned short* __restrict__ f1_bf,   // [512][288] bf16
    const float* __restrict__ f1_b,
    const float* __restrict__ lnf_g, const float* __restrict__ lnf_b,
    const float* __restrict__ f2_w, const float* __restrict__ f2_b,
    float* __restrict__ out)
{
  __shared__ __align__(16) unsigned short s_fin[16][296];
  __shared__ __align__(16) float s_pre[16][520];
  const int tid = threadIdx.x;
  const int r0  = blockIdx.x * 16;
  const int wid = tid >> 6, lane = tid & 63;
  const int lr  = lane & 15, lg = lane >> 4;

  // stage 16 rows x 288 bf16
  for (int i = tid; i < 16*36; i += 256){
    int r = i / 36, cc = (i % 36) * 8;
    *(short8*)&s_fin[r][cc] = *(const short8*)(fc_in + (size_t)(r0 + r) * 288 + cc);
  }
  __syncthreads();

  // GEMM: M=16, N=512 (wave w cols 128w..128w+128), K=288
  {
    f32x4 acc[8];
    const f32x4 z = {0.f, 0.f, 0.f, 0.f};
    #pragma unroll
    for (int t = 0; t < 8; t++) acc[t] = z;
    #pragma unroll
    for (int kk = 0; kk < 9; kk++){
      const int k0 = kk*32 + lg*8;
      short8 a = *(const short8*)&s_fin[lr][k0];
      #pragma unroll
      for (int t = 0; t < 8; t++){
        short8 bw = *(const short8*)(f1_bf + (size_t)(128*wid + 16*t + lr) * 288 + k0);
        acc[t] = __builtin_amdgcn_mfma_f32_16x16x32_bf16(a, bw, acc[t], 0, 0, 0);
      }
    }
    #pragma unroll
    for (int t = 0; t < 8; t++){
      const int col = 128*wid + 16*t + lr;
      const float bias = f1_b[col];
      #pragma unroll
      for (int j = 0; j < 4; j++){
        const int row = 4*lg + j;
        s_pre[row][col] = acc[t][j] + bias;
      }
    }
  }
  __syncthreads();

  // LNf + lrelu + dot(f2_w): wave w rows 4w..4w+4, lane covers 8 cols
  {
    const int c0 = lane * 8;
    float g8[8], b8[8], w8[8];
    #pragma unroll
    for (int j = 0; j < 8; j++){ g8[j] = lnf_g[c0+j]; b8[j] = lnf_b[c0+j]; w8[j] = f2_w[c0+j]; }
    for (int r = wid*4; r < wid*4 + 4; r++){
      float x[8];
      #pragma unroll
      for (int j = 0; j < 8; j++) x[j] = s_pre[r][c0+j];
      float s = 0.f, s2 = 0.f;
      #pragma unroll
      for (int j = 0; j < 8; j++){ s += x[j]; s2 += x[j]*x[j]; }
      #pragma unroll
      for (int m = 1; m < 64; m <<= 1){ s += __shfl_xor(s, m, 64); s2 += __shfl_xor(s2, m, 64); }
      float mean = s * (1.f/512.f);
      float var  = s2 * (1.f/512.f) - mean*mean;
      float rstd = rsqrtf(var + LN_EPS);
      float dot = 0.f;
      #pragma unroll
      for (int j = 0; j < 8; j++){
        float y = (x[j]-mean)*rstd*g8[j] + b8[j];
        y = (y >= 0.f) ? y : NSLOPE*y;
        dot += y * w8[j];
      }
      #pragma unroll
      for (int m = 1; m < 64; m <<= 1) dot += __shfl_xor(dot, m, 64);
      if (lane == 0) out[r0 + r] = dot + f2_b[0];
    }
  }
}

extern "C" void kernel_launch(void* const* d_in, const int* in_sizes, int n_in,
                              void* d_out, int out_size, void* d_ws, size_t ws_size,
                              hipStream_t stream)
{
  const float* x_feats = (const float*)d_in[0];
  const int*   actions = (const int*)d_in[1];
  const float* fc1_w = (const float*)d_in[2];  const float* fc1_b = (const float*)d_in[3];
  const float* ln1_g = (const float*)d_in[4];  const float* ln1_b = (const float*)d_in[5];
  const float* fc2_w = (const float*)d_in[6];  const float* fc2_b = (const float*)d_in[7];
  const float* ln2_g = (const float*)d_in[8];  const float* ln2_b = (const float*)d_in[9];
  const float* fc3_w = (const float*)d_in[10]; const float* fc3_b = (const float*)d_in[11];
  const float* f1_w  = (const float*)d_in[12]; const float* f1_b  = (const float*)d_in[13];
  const float* lnf_g = (const float*)d_in[14]; const float* lnf_b = (const float*)d_in[15];
  const float* f2_w  = (const float*)d_in[16]; const float* f2_b  = (const float*)d_in[17];

  const int B = in_sizes[1];  // 4096

  unsigned short* fc2_bf = (unsigned short*)d_ws;
  unsigned short* fc3_bf = fc2_bf + 256*256;
  unsigned short* f1_bf  = fc3_bf + 128*256;
  unsigned short* fc_in  = f1_bf  + 512*288;

  qnet_prep<<<dim3(960), dim3(256), 0, stream>>>(fc2_w, fc3_w, f1_w, fc2_bf, fc3_bf, f1_bf);
  qnet_main<<<dim3(B), dim3(256), 0, stream>>>(x_feats, actions,
      fc1_w, fc1_b, ln1_g, ln1_b, fc2_bf, fc2_b, ln2_g, ln2_b, fc3_bf, fc3_b, fc_in);
  qnet_head<<<dim3(B/16), dim3(256), 0, stream>>>(fc_in, f1_bf, f1_b, lnf_g, lnf_b, f2_w, f2_b,
      (float*)d_out);
}

// Round 2
// 177.340 us; speedup vs baseline: 1.3618x; 1.3618x over previous
//
#include <hip/hip_runtime.h>

typedef __attribute__((ext_vector_type(8))) short short8;
typedef __attribute__((ext_vector_type(4))) float f32x4;

#define LN_EPS 1e-5f
#define NSLOPE 0.01f
#define SROW 264   // shorts per s_act row (528B, 16B-aligned, 132 dwords)

static __device__ __forceinline__ unsigned short f2bf(float f){
  union { float f; unsigned int u; } v; v.f = f;
  unsigned int u = v.u;
  unsigned int r = (u + 0x7FFFu + ((u >> 16) & 1u)) >> 16;
  return (unsigned short)r;
}
static __device__ __forceinline__ float bf2f(unsigned short h){
  union { unsigned int u; float f; } v; v.u = ((unsigned int)h) << 16;
  return v.f;
}

// ---------------- prep: convert weights to bf16; pad f1_w K 264->288, fc1_w K 8->32
__global__ void qnet_prep(const float* __restrict__ fc1_w, const float* __restrict__ fc2_w,
                          const float* __restrict__ fc3_w, const float* __restrict__ f1_w,
                          unsigned short* __restrict__ fc1w_bf, unsigned short* __restrict__ fc2_bf,
                          unsigned short* __restrict__ fc3_bf, unsigned short* __restrict__ f1_bf){
  int i = blockIdx.x * 256 + threadIdx.x;
  if (i < 65536) {
    fc2_bf[i] = f2bf(fc2_w[i]);
  } else if (i < 98304) {
    int j = i - 65536;
    fc3_bf[j] = f2bf(fc3_w[j]);
  } else if (i < 245760) {
    int j = i - 98304;
    int o = j / 288, k = j % 288;
    f1_bf[j] = (k < 264) ? f2bf(f1_w[o*264 + k]) : (unsigned short)0;
  } else {
    int j = i - 245760;           // < 8192
    int c = j >> 5, k = j & 31;
    fc1w_bf[j] = (k < 8) ? f2bf(fc1_w[c*8 + k]) : (unsigned short)0;
  }
}

// ---------------- in-place LN + leaky-relu over 256 cols, 4 threads per row --
static __device__ __forceinline__ void ln_lrelu_inplace(
    unsigned short (*s_act)[SROW], const float* __restrict__ g,
    const float* __restrict__ bt, int tid)
{
  const int r = tid >> 2, q = tid & 3;
  short8 v[8];
  #pragma unroll
  for (int k = 0; k < 4; k++)
    #pragma unroll
    for (int i = 0; i < 2; i++)
      v[k*2+i] = *(const short8*)&s_act[r][q*16 + 64*k + i*8];

  float s = 0.f, s2 = 0.f;
  #pragma unroll
  for (int u = 0; u < 8; u++)
    #pragma unroll
    for (int j = 0; j < 8; j++){
      float x = bf2f((unsigned short)v[u][j]);
      s += x; s2 = fmaf(x, x, s2);
    }
  s  += __shfl_xor(s, 1, 64);  s  += __shfl_xor(s, 2, 64);
  s2 += __shfl_xor(s2, 1, 64); s2 += __shfl_xor(s2, 2, 64);
  const float mean = s * (1.f/256.f);
  const float var  = fmaf(s2, 1.f/256.f, -mean*mean);
  const float rstd = rsqrtf(var + LN_EPS);

  #pragma unroll
  for (int k = 0; k < 4; k++)
    #pragma unroll
    for (int i = 0; i < 2; i++){
      const int c0 = q*16 + 64*k + i*8;
      float4 g0 = *(const float4*)(g  + c0), g1 = *(const float4*)(g  + c0 + 4);
      float4 b0 = *(const float4*)(bt + c0), b1 = *(const float4*)(bt + c0 + 4);
      float gg[8] = {g0.x,g0.y,g0.z,g0.w,g1.x,g1.y,g1.z,g1.w};
      float bb[8] = {b0.x,b0.y,b0.z,b0.w,b1.x,b1.y,b1.z,b1.w};
      const short8 x8 = v[k*2+i];
      short8 o;
      #pragma unroll
      for (int j = 0; j < 8; j++){
        float a = rstd * gg[j];
        float y = fmaf(bf2f((unsigned short)x8[j]) - mean, a, bb[j]);
        y = (y >= 0.f) ? y : NSLOPE * y;
        o[j] = (short)f2bf(y);
      }
      *(short8*)&s_act[r][c0] = o;
    }
}

// ---------------- main fused kernel: one block per b ------------------------
__global__ __launch_bounds__(256, 4) void qnet_main(
    const float* __restrict__ x_feats, const int* __restrict__ actions,
    const unsigned short* __restrict__ fc1w_bf, const float* __restrict__ fc1_b,
    const float* __restrict__ ln1_g, const float* __restrict__ ln1_b,
    const unsigned short* __restrict__ fc2_bf, const float* __restrict__ fc2_b,
    const float* __restrict__ ln2_g, const float* __restrict__ ln2_b,
    const unsigned short* __restrict__ fc3_bf, const float* __restrict__ fc3_b,
    unsigned short* __restrict__ fc_in)
{
  __shared__ float s_cur[4];
  __shared__ __align__(16) float s_nb[64][12];
  __shared__ float s_mask[64];
  __shared__ __align__(16) unsigned short s_act[64][SROW];

  const int tid  = threadIdx.x;
  const int b    = blockIdx.x;
  const int wid  = tid >> 6, lane = tid & 63;
  const int lr   = lane & 15, lg = lane >> 4;

  // ---- phase 0: load x row (3 + 64*5 floats) ----
  const float* xr = x_feats + (size_t)b * 323;
  for (int i = tid; i < 323; i += 256){
    float v = xr[i];
    if (i < 3) s_cur[i] = v;
    else { int j = i - 3; s_nb[j / 5][j % 5] = v; }
  }
  __syncthreads();
  if (tid < 64){
    s_mask[tid] = (s_nb[tid][0] != 0.f || s_nb[tid][1] != 0.f || s_nb[tid][2] != 0.f ||
                   s_nb[tid][3] != 0.f || s_nb[tid][4] != 0.f) ? 1.f : 0.f;
  }

  // ---- stage 1: fc1 (K=8 padded to 32) via MFMA; wave w -> cols 64w..64w+63 --
  {
    short8 a1[4];
    #pragma unroll
    for (int m = 0; m < 4; m++){
      const int row = 16*m + lr;
      float v0=0.f,v1=0.f,v2=0.f,v3=0.f,v4=0.f,v5=0.f,v6=0.f,v7=0.f;
      if (lg == 0){
        v0 = s_cur[0]; v1 = s_cur[1]; v2 = s_cur[2];
        float4 nb = *(const float4*)&s_nb[row][0];
        v3 = nb.x; v4 = nb.y; v5 = nb.z; v6 = nb.w; v7 = s_nb[row][4];
      }
      short8 t;
      t[0]=(short)f2bf(v0); t[1]=(short)f2bf(v1); t[2]=(short)f2bf(v2); t[3]=(short)f2bf(v3);
      t[4]=(short)f2bf(v4); t[5]=(short)f2bf(v5); t[6]=(short)f2bf(v6); t[7]=(short)f2bf(v7);
      a1[m] = t;
    }
    f32x4 acc[4][4];
    const f32x4 z = {0.f,0.f,0.f,0.f};
    #pragma unroll
    for (int m = 0; m < 4; m++)
      #pragma unroll
      for (int t4 = 0; t4 < 4; t4++) acc[m][t4] = z;
    #pragma unroll
    for (int t4 = 0; t4 < 4; t4++){
      short8 bw = *(const short8*)(fc1w_bf + (size_t)(64*wid + 16*t4 + lr)*32 + lg*8);
      #pragma unroll
      for (int m = 0; m < 4; m++)
        acc[m][t4] = __builtin_amdgcn_mfma_f32_16x16x32_bf16(a1[m], bw, acc[m][t4], 0, 0, 0);
    }
    #pragma unroll
    for (int t4 = 0; t4 < 4; t4++){
      const int col = 64*wid + 16*t4 + lr;
      const float bias = fc1_b[col];
      #pragma unroll
      for (int m = 0; m < 4; m++)
        #pragma unroll
        for (int j = 0; j < 4; j++)
          s_act[16*m + 4*lg + j][col] = f2bf(acc[m][t4][j] + bias);
    }
  }
  __syncthreads();
  ln_lrelu_inplace(s_act, ln1_g, ln1_b, tid);
  __syncthreads();

  // ---- stage 2: fc2 (256->256) MFMA; wave w -> cols 64w..64w+63 -------------
  {
    f32x4 acc[4][4];
    const f32x4 z = {0.f,0.f,0.f,0.f};
    #pragma unroll
    for (int m = 0; m < 4; m++)
      #pragma unroll
      for (int t4 = 0; t4 < 4; t4++) acc[m][t4] = z;
    #pragma unroll
    for (int kk = 0; kk < 8; kk++){
      const int k0 = kk*32 + lg*8;
      short8 a[4];
      #pragma unroll
      for (int m = 0; m < 4; m++) a[m] = *(const short8*)&s_act[16*m + lr][k0];
      #pragma unroll
      for (int t4 = 0; t4 < 4; t4++){
        short8 bw = *(const short8*)(fc2_bf + (size_t)(64*wid + 16*t4 + lr)*256 + k0);
        #pragma unroll
        for (int m = 0; m < 4; m++)
          acc[m][t4] = __builtin_amdgcn_mfma_f32_16x16x32_bf16(a[m], bw, acc[m][t4], 0, 0, 0);
      }
    }
    __syncthreads();   // all waves finished reading act1
    #pragma unroll
    for (int t4 = 0; t4 < 4; t4++){
      const int col = 64*wid + 16*t4 + lr;
      const float bias = fc2_b[col];
      #pragma unroll
      for (int m = 0; m < 4; m++)
        #pragma unroll
        for (int j = 0; j < 4; j++)
          s_act[16*m + 4*lg + j][col] = f2bf(acc[m][t4][j] + bias);
    }
  }
  __syncthreads();
  ln_lrelu_inplace(s_act, ln2_g, ln2_b, tid);
  __syncthreads();

  // ---- stage 3: fc3 (256->128) MFMA; wave w -> cols 32w..32w+31 -------------
  {
    f32x4 acc[4][2];
    const f32x4 z = {0.f,0.f,0.f,0.f};
    #pragma unroll
    for (int m = 0; m < 4; m++){ acc[m][0] = z; acc[m][1] = z; }
    #pragma unroll
    for (int kk = 0; kk < 8; kk++){
      const int k0 = kk*32 + lg*8;
      short8 a[4];
      #pragma unroll
      for (int m = 0; m < 4; m++) a[m] = *(const short8*)&s_act[16*m + lr][k0];
      #pragma unroll
      for (int t4 = 0; t4 < 2; t4++){
        short8 bw = *(const short8*)(fc3_bf + (size_t)(32*wid + 16*t4 + lr)*256 + k0);
        #pragma unroll
        for (int m = 0; m < 4; m++)
          acc[m][t4] = __builtin_amdgcn_mfma_f32_16x16x32_bf16(a[m], bw, acc[m][t4], 0, 0, 0);
      }
    }
    __syncthreads();   // all waves finished reading act2
    #pragma unroll
    for (int t4 = 0; t4 < 2; t4++){
      const int col = 32*wid + 16*t4 + lr;
      const float bias = fc3_b[col];
      #pragma unroll
      for (int m = 0; m < 4; m++)
        #pragma unroll
        for (int j = 0; j < 4; j++)
          s_act[16*m + 4*lg + j][col] = f2bf(acc[m][t4][j] + bias);  // embeds cols 0..127
    }
  }
  __syncthreads();

  // ---- phase 4: masked mean-pool + gather -> fc_in[b][288] -----------------
  {
    const int aidx = actions[b];
    unsigned short* fo = fc_in + (size_t)b * 288;
    if (tid < 128){
      float accp = 0.f, cnt = 0.f;
      for (int n = 0; n < 64; n++){
        float m = s_mask[n];
        cnt  += m;
        accp += m * bf2f(s_act[n][tid]);
      }
      cnt = fmaxf(cnt, 1.f);
      fo[131 + tid] = f2bf(accp / cnt);   // pooled
      fo[3 + tid]   = s_act[aidx][tid];   // chosen embed
    } else {
      const int t = tid - 128;
      if (t < 3)       fo[t] = f2bf(s_cur[t]);
      else if (t < 8)  fo[259 + (t-3)] = f2bf(s_nb[aidx][t-3]);
      else if (t < 32) fo[264 + (t-8)] = 0;   // zero pad K->288
    }
  }
}

// ---------------- head: fc_in[B][288] -> f1 -> LN -> lrelu -> f2 -> out[B] --
__global__ __launch_bounds__(256, 2) void qnet_head(
    const unsigned short* __restrict__ fc_in,   // [B][288] bf16
    const unsigned short* __restrict__ f1_bf,   // [512][288] bf16
    const float* __restrict__ f1_b,
    const float* __restrict__ lnf_g, const float* __restrict__ lnf_b,
    const float* __restrict__ f2_w, const float* __restrict__ f2_b,
    float* __restrict__ out)
{
  __shared__ __align__(16) unsigned short s_fin[16][296];
  __shared__ __align__(16) float s_pre[16][520];
  const int tid = threadIdx.x;
  const int r0  = blockIdx.x * 16;
  const int wid = tid >> 6, lane = tid & 63;
  const int lr  = lane & 15, lg = lane >> 4;

  for (int i = tid; i < 16*36; i += 256){
    int r = i / 36, cc = (i % 36) * 8;
    *(short8*)&s_fin[r][cc] = *(const short8*)(fc_in + (size_t)(r0 + r) * 288 + cc);
  }
  __syncthreads();

  {
    f32x4 acc[8];
    const f32x4 z = {0.f, 0.f, 0.f, 0.f};
    #pragma unroll
    for (int t = 0; t < 8; t++) acc[t] = z;
    #pragma unroll
    for (int kk = 0; kk < 9; kk++){
      const int k0 = kk*32 + lg*8;
      short8 a = *(const short8*)&s_fin[lr][k0];
      #pragma unroll
      for (int t = 0; t < 8; t++){
        short8 bw = *(const short8*)(f1_bf + (size_t)(128*wid + 16*t + lr) * 288 + k0);
        acc[t] = __builtin_amdgcn_mfma_f32_16x16x32_bf16(a, bw, acc[t], 0, 0, 0);
      }
    }
    #pragma unroll
    for (int t = 0; t < 8; t++){
      const int col = 128*wid + 16*t + lr;
      const float bias = f1_b[col];
      #pragma unroll
      for (int j = 0; j < 4; j++){
        const int row = 4*lg + j;
        s_pre[row][col] = acc[t][j] + bias;
      }
    }
  }
  __syncthreads();

  {
    const int c0 = lane * 8;
    float g8[8], b8[8], w8[8];
    #pragma unroll
    for (int j = 0; j < 8; j++){ g8[j] = lnf_g[c0+j]; b8[j] = lnf_b[c0+j]; w8[j] = f2_w[c0+j]; }
    for (int r = wid*4; r < wid*4 + 4; r++){
      float x[8];
      #pragma unroll
      for (int j = 0; j < 8; j++) x[j] = s_pre[r][c0+j];
      float s = 0.f, s2 = 0.f;
      #pragma unroll
      for (int j = 0; j < 8; j++){ s += x[j]; s2 += x[j]*x[j]; }
      #pragma unroll
      for (int m = 1; m < 64; m <<= 1){ s += __shfl_xor(s, m, 64); s2 += __shfl_xor(s2, m, 64); }
      float mean = s * (1.f/512.f);
      float var  = s2 * (1.f/512.f) - mean*mean;
      float rstd = rsqrtf(var + LN_EPS);
      float dot = 0.f;
      #pragma unroll
      for (int j = 0; j < 8; j++){
        float y = (x[j]-mean)*rstd*g8[j] + b8[j];
        y = (y >= 0.f) ? y : NSLOPE*y;
        dot += y * w8[j];
      }
      #pragma unroll
      for (int m = 1; m < 64; m <<= 1) dot += __shfl_xor(dot, m, 64);
      if (lane == 0) out[r0 + r] = dot + f2_b[0];
    }
  }
}

extern "C" void kernel_launch(void* const* d_in, const int* in_sizes, int n_in,
                              void* d_out, int out_size, void* d_ws, size_t ws_size,
                              hipStream_t stream)
{
  const float* x_feats = (const float*)d_in[0];
  const int*   actions = (const int*)d_in[1];
  const float* fc1_w = (const float*)d_in[2];  const float* fc1_b = (const float*)d_in[3];
  const float* ln1_g = (const float*)d_in[4];  const float* ln1_b = (const float*)d_in[5];
  const float* fc2_w = (const float*)d_in[6];  const float* fc2_b = (const float*)d_in[7];
  const float* ln2_g = (const float*)d_in[8];  const float* ln2_b = (const float*)d_in[9];
  const float* fc3_w = (const float*)d_in[10]; const float* fc3_b = (const float*)d_in[11];
  const float* f1_w  = (const float*)d_in[12]; const float* f1_b  = (const float*)d_in[13];
  const float* lnf_g = (const float*)d_in[14]; const float* lnf_b = (const float*)d_in[15];
  const float* f2_w  = (const float*)d_in[16]; const float* f2_b  = (const float*)d_in[17];

  const int B = in_sizes[1];  // 4096

  unsigned short* fc2_bf  = (unsigned short*)d_ws;
  unsigned short* fc3_bf  = fc2_bf + 256*256;
  unsigned short* f1_bf   = fc3_bf + 128*256;
  unsigned short* fc1w_bf = f1_bf  + 512*288;
  unsigned short* fc_in   = fc1w_bf + 256*32;

  qnet_prep<<<dim3(992), dim3(256), 0, stream>>>(fc1_w, fc2_w, fc3_w, f1_w,
      fc1w_bf, fc2_bf, fc3_bf, f1_bf);
  qnet_main<<<dim3(B), dim3(256), 0, stream>>>(x_feats, actions,
      fc1w_bf, fc1_b, ln1_g, ln1_b, fc2_bf, fc2_b, ln2_g, ln2_b, fc3_bf, fc3_b, fc_in);
  qnet_head<<<dim3(B/16), dim3(256), 0, stream>>>(fc_in, f1_bf, f1_b, lnf_g, lnf_b, f2_w, f2_b,
      (float*)d_out);
}